// Round 1
// 512.482 us; speedup vs baseline: 1.0611x; 1.0611x over previous
//
#include <hip/hip_runtime.h>
#include <math.h>

typedef unsigned int u32;
typedef __attribute__((ext_vector_type(8))) short bf16x8;
typedef __attribute__((ext_vector_type(4))) float floatx4;

constexpr int NN = 100000;
constexpr int EE = 1600000;
constexpr int IND = 256;
constexpr int F1 = 32;
constexpr int HF = 128;   // H*F1
constexpr int C  = 40;
constexpr float SLOPE = 0.2f;

constexpr int SCAN_BLOCKS = 100;
constexpr int SCAN_CHUNK  = 1000;   // SCAN_BLOCKS * SCAN_CHUNK == NN

constexpr int SC_NW    = 8;
constexpr int SC_WINW  = (NN + SC_NW - 1) / SC_NW;
constexpr int SC_CHUNK = 8192;
constexpr int SC_NCHUNK = (EE + SC_CHUNK - 1) / SC_CHUNK;

constexpr int H2ROW = 24;  // u32 per h2b row: 20 bf16x2 pairs + el2 bits + pad

__device__ __forceinline__ u32 f2bf(float f) {
    u32 u = __float_as_uint(f);
    return (u + 0x7fffu + ((u >> 16) & 1u)) >> 16;
}
__device__ __forceinline__ float bf_lo(u32 v) { return __uint_as_float(v << 16); }
__device__ __forceinline__ float bf_hi(u32 v) { return __uint_as_float(v & 0xffff0000u); }

// ================= CSR build =================
__global__ __launch_bounds__(256) void k_hist(const int* __restrict__ dst,
                                              int* __restrict__ deg) {
    int e = blockIdx.x * 256 + threadIdx.x;
    if (e < EE) atomicAdd(&deg[dst[e]], 1);
}

__global__ __launch_bounds__(256) void k_scan1(const int* __restrict__ deg,
                                               int* __restrict__ blk_sums) {
    __shared__ int wsum[4];
    const int lane = threadIdx.x & 63, wid = threadIdx.x >> 6;
    const int base = blockIdx.x * SCAN_CHUNK;
    int s = 0;
    for (int i = threadIdx.x; i < SCAN_CHUNK; i += 256) s += deg[base + i];
    #pragma unroll
    for (int m = 1; m < 64; m <<= 1) s += __shfl_xor(s, m, 64);
    if (lane == 0) wsum[wid] = s;
    __syncthreads();
    if (threadIdx.x == 0)
        blk_sums[blockIdx.x] = wsum[0] + wsum[1] + wsum[2] + wsum[3];
}

__global__ __launch_bounds__(128) void k_scan2(int* __restrict__ blk_sums) {
    __shared__ int lds[128];
    const int tid = threadIdx.x;
    int v = (tid < SCAN_BLOCKS) ? blk_sums[tid] : 0;
    lds[tid] = v;
    __syncthreads();
    for (int off = 1; off < 128; off <<= 1) {
        int t = (tid >= off) ? lds[tid - off] : 0;
        __syncthreads();
        lds[tid] += t;
        __syncthreads();
    }
    if (tid < SCAN_BLOCKS) blk_sums[tid] = (tid == 0) ? 0 : lds[tid - 1];
}

__global__ __launch_bounds__(256) void k_scan3(const int* __restrict__ deg,
                                               const int* __restrict__ blk_off,
                                               int* __restrict__ row_ptr,
                                               int* __restrict__ cursor) {
    __shared__ int wsum[4];
    const int tid = threadIdx.x, lane = tid & 63, wid = tid >> 6;
    const int base = blockIdx.x * SCAN_CHUNK;
    const int g0 = tid * 4;
    int v[4];
    #pragma unroll
    for (int i = 0; i < 4; ++i) {
        int gi = g0 + i;
        v[i] = (gi < SCAN_CHUNK) ? deg[base + gi] : 0;
    }
    const int tsum = v[0] + v[1] + v[2] + v[3];
    int s = tsum;
    #pragma unroll
    for (int off = 1; off < 64; off <<= 1) {
        int t = __shfl_up(s, off, 64);
        if (lane >= off) s += t;
    }
    if (lane == 63) wsum[wid] = s;
    __syncthreads();
    int woff = 0;
    for (int w = 0; w < wid; ++w) woff += wsum[w];
    int run = blk_off[blockIdx.x] + woff + (s - tsum);
    #pragma unroll
    for (int i = 0; i < 4; ++i) {
        int gi = g0 + i;
        int idx = base + gi;
        if (gi < SCAN_CHUNK) {
            row_ptr[idx] = run;
            cursor[idx] = run;
            run += v[i];
            if (idx == NN - 1) row_ptr[NN] = run;
        }
    }
}

__global__ __launch_bounds__(256) void k_scatter(const int* __restrict__ src,
                                                 const int* __restrict__ dst,
                                                 int* __restrict__ cursor,
                                                 int* __restrict__ col_src) {
    const int w = blockIdx.x & (SC_NW - 1);
    const int chunk = blockIdx.x >> 3;
    const int lo = w * SC_WINW, hi = lo + SC_WINW;
    const int base = chunk * SC_CHUNK;
    const int lim = min(base + SC_CHUNK, EE);
    for (int i = base + threadIdx.x; i < lim; i += 256) {
        int d = dst[i];
        if (d >= lo && d < hi) {
            int p = atomicAdd(&cursor[d], 1);
            col_src[p] = src[i];
        }
    }
}

// ================= GEMM1 (MFMA bf16): h1b = bf16(feat @ W1), + el1/er1 =================
__global__ __launch_bounds__(256) void k_gemm1(const float* __restrict__ feat,
                                               const float* __restrict__ W1,
                                               const float* __restrict__ al1,
                                               const float* __restrict__ ar1,
                                               u32* __restrict__ h1b,
                                               float* __restrict__ el1,
                                               float* __restrict__ er1) {
    __shared__ u32 w1t[128 * 128];
    const int tid = threadIdx.x;
    {
        const int n = tid & 127;
        const int o0 = (tid >> 7) * 16;
        for (int i = 0; i < 16; ++i) {
            const int o = o0 + i;
            float f0 = W1[(size_t)(o * 8 + 0) * HF + n];
            float f1 = W1[(size_t)(o * 8 + 1) * HF + n];
            float f2 = W1[(size_t)(o * 8 + 2) * HF + n];
            float f3 = W1[(size_t)(o * 8 + 3) * HF + n];
            float f4 = W1[(size_t)(o * 8 + 4) * HF + n];
            float f5 = W1[(size_t)(o * 8 + 5) * HF + n];
            float f6 = W1[(size_t)(o * 8 + 6) * HF + n];
            float f7 = W1[(size_t)(o * 8 + 7) * HF + n];
            uint4 p;
            p.x = (f2bf(f1) << 16) | f2bf(f0);
            p.y = (f2bf(f3) << 16) | f2bf(f2);
            p.z = (f2bf(f5) << 16) | f2bf(f4);
            p.w = (f2bf(f7) << 16) | f2bf(f6);
            *(uint4*)&w1t[n * 128 + ((o ^ (n & 7)) << 2)] = p;
        }
    }
    __syncthreads();

    const int w = tid >> 6, lane = tid & 63;
    const int quad = lane >> 4, l15 = lane & 15;
    const int rbase = blockIdx.x * 128 + w * 32;

    // attention vectors for epilogue
    float alv[4][2], arv[4][2];
    #pragma unroll
    for (int h = 0; h < 4; ++h) {
        alv[h][0] = al1[h * F1 + l15];
        alv[h][1] = al1[h * F1 + 16 + l15];
        arv[h][0] = ar1[h * F1 + l15];
        arv[h][1] = ar1[h * F1 + 16 + l15];
    }

    floatx4 acc[2][8] = {};
    for (int ks = 0; ks < 8; ++ks) {
        bf16x8 a[2];
        #pragma unroll
        for (int ri = 0; ri < 2; ++ri) {
            int row = rbase + ri * 16 + l15;
            row = row < NN ? row : NN - 1;
            const size_t base = (size_t)row * IND + ks * 32 + quad * 8;
            const float4 f0 = *(const float4*)&feat[base];
            const float4 f1 = *(const float4*)&feat[base + 4];
            uint4 p;
            p.x = (f2bf(f0.y) << 16) | f2bf(f0.x);
            p.y = (f2bf(f0.w) << 16) | f2bf(f0.z);
            p.z = (f2bf(f1.y) << 16) | f2bf(f1.x);
            p.w = (f2bf(f1.w) << 16) | f2bf(f1.z);
            a[ri] = *(bf16x8*)&p;
        }
        const int g = ks * 4 + quad;
        #pragma unroll
        for (int ci = 0; ci < 8; ++ci) {
            const int n = ci * 16 + l15;
            uint4 bw = *(const uint4*)&w1t[n * 128 + ((g ^ (n & 7)) << 2)];
            bf16x8 b = *(bf16x8*)&bw;
            acc[0][ci] = __builtin_amdgcn_mfma_f32_16x16x32_bf16(a[0], b, acc[0][ci], 0, 0, 0);
            acc[1][ci] = __builtin_amdgcn_mfma_f32_16x16x32_bf16(a[1], b, acc[1][ci], 0, 0, 0);
        }
    }

    // ---- epilogue: pack h1b + compute el1/er1 from f32 acc ----
    #pragma unroll
    for (int ri = 0; ri < 2; ++ri) {
        #pragma unroll
        for (int r = 0; r < 4; ++r) {
            const int row = rbase + ri * 16 + quad * 4 + r;
            const bool rok = row < NN;
            #pragma unroll
            for (int h = 0; h < 4; ++h) {
                float pe = acc[ri][2 * h][r] * alv[h][0] + acc[ri][2 * h + 1][r] * alv[h][1];
                float pr = acc[ri][2 * h][r] * arv[h][0] + acc[ri][2 * h + 1][r] * arv[h][1];
                #pragma unroll
                for (int m = 1; m < 16; m <<= 1) {
                    pe += __shfl_xor(pe, m, 64);
                    pr += __shfl_xor(pr, m, 64);
                }
                if (l15 == 0 && rok) {
                    el1[row * 4 + h] = pe;
                    er1[row * 4 + h] = pr;
                }
            }
            #pragma unroll
            for (int ci = 0; ci < 8; ++ci) {
                float v = acc[ri][ci][r];
                float vn = __shfl_xor(v, 1, 64);
                if (!(lane & 1) && rok) {
                    h1b[(size_t)row * 64 + ci * 8 + (l15 >> 1)] =
                        (f2bf(vn) << 16) | f2bf(v);
                }
            }
        }
    }
}

// ================= layer-1 aggregation: wave per dst, 4 edges/iter (16 lanes each) ====
// h1b row = 64 u32 (256B). Lane layout: g = lane>>4 (edge slot 0..3), li = lane&15.
// Lane loads dwordx4 at u32 offset 4*li -> features 8li..8li+7 (all in head li>>2).
// One vmem inst fetches 4 rows; exp/addr/ssum shared 4-ways. Cross-group combine
// via shfl_xor(16/32) once per dst.
__global__ __launch_bounds__(256) void k_agg1(const int* __restrict__ row_ptr,
                                              const int* __restrict__ col_src,
                                              const u32* __restrict__ h1b,
                                              const float* __restrict__ el1,
                                              const float* __restrict__ er1,
                                              const float* __restrict__ b1,
                                              u32* __restrict__ x_b) {
    const int wid = threadIdx.x >> 6, lane = threadIdx.x & 63;
    const int d = blockIdx.x * 4 + wid;
    if (d >= NN) return;
    const int g = lane >> 4;       // edge slot within wave
    const int li = lane & 15;      // feature-quad within row
    const int head = li >> 2;      // features 8li..8li+7 all belong to head li>>2
    const float erd = er1[d * 4 + head];
    const int beg = row_ptr[d], end = row_ptr[d + 1];

    float acc0 = 0.f, acc1 = 0.f, acc2 = 0.f, acc3 = 0.f;
    float acc4 = 0.f, acc5 = 0.f, acc6 = 0.f, acc7 = 0.f;
    float ssum = 0.f;

    auto body = [&](int e, bool all_valid) {
        const int ec = e < EE ? e : EE - 1;
        const int s = col_src[ec];
        const uint4 v = *(const uint4*)&h1b[(size_t)s * 64 + 4 * li];
        float c = el1[s * 4 + head] + erd;
        c = fmaxf(c, SLOPE * c);
        if (!all_valid && e >= end) c = -1e30f;   // exp -> 0: dead slot
        const float w = __expf(c);
        ssum += w;
        acc0 += w * bf_lo(v.x); acc1 += w * bf_hi(v.x);
        acc2 += w * bf_lo(v.y); acc3 += w * bf_hi(v.y);
        acc4 += w * bf_lo(v.z); acc5 += w * bf_hi(v.z);
        acc6 += w * bf_lo(v.w); acc7 += w * bf_hi(v.w);
    };

    int e0 = beg;
    for (; e0 + 8 <= end; e0 += 8) {   // 8 edges in flight (2 quad-iters)
        body(e0 + g, true);
        body(e0 + 4 + g, true);
    }
    for (; e0 < end; e0 += 4) body(e0 + g, false);

    // combine the 4 edge groups (same li across groups holds same features)
    #pragma unroll
    for (int m = 16; m < 64; m <<= 1) {
        acc0 += __shfl_xor(acc0, m, 64);
        acc1 += __shfl_xor(acc1, m, 64);
        acc2 += __shfl_xor(acc2, m, 64);
        acc3 += __shfl_xor(acc3, m, 64);
        acc4 += __shfl_xor(acc4, m, 64);
        acc5 += __shfl_xor(acc5, m, 64);
        acc6 += __shfl_xor(acc6, m, 64);
        acc7 += __shfl_xor(acc7, m, 64);
        ssum += __shfl_xor(ssum, m, 64);
    }

    if (g == 0) {
        const float inv = ssum > 0.f ? 1.f / ssum : 0.f;
        const float4 ba = *(const float4*)&b1[8 * li];
        const float4 bb = *(const float4*)&b1[8 * li + 4];
        float r0 = acc0 * inv + ba.x, r1 = acc1 * inv + ba.y;
        float r2 = acc2 * inv + ba.z, r3 = acc3 * inv + ba.w;
        float r4 = acc4 * inv + bb.x, r5 = acc5 * inv + bb.y;
        float r6 = acc6 * inv + bb.z, r7 = acc7 * inv + bb.w;
        r0 = r0 > 0.f ? r0 : expm1f(r0);
        r1 = r1 > 0.f ? r1 : expm1f(r1);
        r2 = r2 > 0.f ? r2 : expm1f(r2);
        r3 = r3 > 0.f ? r3 : expm1f(r3);
        r4 = r4 > 0.f ? r4 : expm1f(r4);
        r5 = r5 > 0.f ? r5 : expm1f(r5);
        r6 = r6 > 0.f ? r6 : expm1f(r6);
        r7 = r7 > 0.f ? r7 : expm1f(r7);
        uint4 p;
        p.x = (f2bf(r1) << 16) | f2bf(r0);
        p.y = (f2bf(r3) << 16) | f2bf(r2);
        p.z = (f2bf(r5) << 16) | f2bf(r4);
        p.w = (f2bf(r7) << 16) | f2bf(r6);
        *(uint4*)&x_b[(size_t)d * 64 + 4 * li] = p;
    }
}

// ================= GEMM2 (MFMA bf16): h2b = pack(x @ [W2|waux_l|waux_r]) =================
// 48 padded cols: 0-39 = classes, 40 = el2 (x·(W2@al2)), 41 = er2, 42-47 zero.
__global__ __launch_bounds__(256) void k_gemm2(const u32* __restrict__ x_b,
                                               const float* __restrict__ W2,
                                               const float* __restrict__ al2,
                                               const float* __restrict__ ar2,
                                               u32* __restrict__ h2b,
                                               float* __restrict__ er2) {
    __shared__ u32 w2t[48 * 64];   // row n: 16 k-octets, octet g at ((g^(n&7))<<2)
    const int tid = threadIdx.x;
    {
        const int o = tid & 15;
        const int n0 = tid >> 4;
        for (int n = n0; n < 48; n += 16) {
            float f[8];
            #pragma unroll
            for (int j = 0; j < 8; ++j) {
                const int k = o * 8 + j;
                float v;
                if (n < C) v = W2[(size_t)k * C + n];
                else if (n == 40) {
                    v = 0.f;
                    for (int c = 0; c < C; ++c) v += W2[(size_t)k * C + c] * al2[c];
                } else if (n == 41) {
                    v = 0.f;
                    for (int c = 0; c < C; ++c) v += W2[(size_t)k * C + c] * ar2[c];
                } else v = 0.f;
                f[j] = v;
            }
            uint4 p;
            p.x = (f2bf(f[1]) << 16) | f2bf(f[0]);
            p.y = (f2bf(f[3]) << 16) | f2bf(f[2]);
            p.z = (f2bf(f[5]) << 16) | f2bf(f[4]);
            p.w = (f2bf(f[7]) << 16) | f2bf(f[6]);
            *(uint4*)&w2t[n * 64 + ((o ^ (n & 7)) << 2)] = p;
        }
    }
    __syncthreads();

    const int w = tid >> 6, lane = tid & 63;
    const int quad = lane >> 4, l15 = lane & 15;
    const int rbase = blockIdx.x * 128 + w * 32;
    floatx4 acc[2][3] = {};

    #pragma unroll
    for (int ks = 0; ks < 4; ++ks) {
        bf16x8 a[2];
        #pragma unroll
        for (int ri = 0; ri < 2; ++ri) {
            int row = rbase + ri * 16 + l15;
            row = row < NN ? row : NN - 1;
            uint4 ax = *(const uint4*)&x_b[(size_t)row * 64 + ks * 16 + quad * 4];
            a[ri] = *(bf16x8*)&ax;
        }
        const int g = ks * 4 + quad;
        #pragma unroll
        for (int ci = 0; ci < 3; ++ci) {
            const int n = ci * 16 + l15;
            uint4 bw = *(const uint4*)&w2t[n * 64 + ((g ^ (n & 7)) << 2)];
            bf16x8 b = *(bf16x8*)&bw;
            acc[0][ci] = __builtin_amdgcn_mfma_f32_16x16x32_bf16(a[0], b, acc[0][ci], 0, 0, 0);
            acc[1][ci] = __builtin_amdgcn_mfma_f32_16x16x32_bf16(a[1], b, acc[1][ci], 0, 0, 0);
        }
    }

    // epilogue: pack h2b rows; col40 -> el2 word, col41 -> er2 array
    #pragma unroll
    for (int ri = 0; ri < 2; ++ri) {
        #pragma unroll
        for (int r = 0; r < 4; ++r) {
            const int row = rbase + ri * 16 + quad * 4 + r;
            const bool rok = row < NN;
            #pragma unroll
            for (int ci = 0; ci < 3; ++ci) {
                float v = acc[ri][ci][r];
                float vn = __shfl_xor(v, 1, 64);
                if (rok) {
                    if (ci < 2) {
                        if (!(lane & 1))
                            h2b[(size_t)row * H2ROW + ci * 8 + (l15 >> 1)] =
                                (f2bf(vn) << 16) | f2bf(v);
                    } else {
                        if (!(lane & 1) && l15 < 8)
                            h2b[(size_t)row * H2ROW + 16 + (l15 >> 1)] =
                                (f2bf(vn) << 16) | f2bf(v);
                        else if (l15 == 8)
                            h2b[(size_t)row * H2ROW + 20] = __float_as_uint(v);
                        else if (l15 == 9)
                            er2[row] = v;
                    }
                }
            }
        }
    }
}

// ================= layer-2 aggregation: wave per dst, 4 edges/iter (16 lanes each) ====
// h2b row = 24 u32 (96B): u32 0..19 = 40 bf16 classes, u32 20 = el2 (f32 bits).
// Lane: g = lane>>4 (edge slot), li = lane&15; li<12 loads dwordx2 at u32 2*li
// (li>=12 clamps to 22 in-row). Only li<10 carries classes (4 per lane).
__global__ __launch_bounds__(256) void k_agg2(const int* __restrict__ row_ptr,
                                              const int* __restrict__ col_src,
                                              const u32* __restrict__ h2b,
                                              const float* __restrict__ er2,
                                              const float* __restrict__ b2,
                                              float* __restrict__ out) {
    const int wid = threadIdx.x >> 6, lane = threadIdx.x & 63;
    const int d = blockIdx.x * 4 + wid;
    if (d >= NN) return;
    const int g = lane >> 4;
    const int li = lane & 15;
    const int o = li < 12 ? 2 * li : 22;    // u32 offset within the 24-u32 row
    const float erd = er2[d];
    const int beg = row_ptr[d], end = row_ptr[d + 1];

    float acc0 = 0.f, acc1 = 0.f, acc2 = 0.f, acc3 = 0.f;
    float ssum = 0.f;

    auto body = [&](int e, bool all_valid) {
        const int ec = e < EE ? e : EE - 1;
        const int s = col_src[ec];
        const u32* rowp = h2b + (size_t)s * H2ROW;
        const uint2 v = *(const uint2*)&rowp[o];
        float c = __uint_as_float(rowp[20]) + erd;
        c = fmaxf(c, SLOPE * c);
        if (!all_valid && e >= end) c = -1e30f;
        const float w = __expf(c);
        ssum += w;
        acc0 += w * bf_lo(v.x); acc1 += w * bf_hi(v.x);
        acc2 += w * bf_lo(v.y); acc3 += w * bf_hi(v.y);
    };

    int e0 = beg;
    for (; e0 + 8 <= end; e0 += 8) {
        body(e0 + g, true);
        body(e0 + 4 + g, true);
    }
    for (; e0 < end; e0 += 4) body(e0 + g, false);

    #pragma unroll
    for (int m = 16; m < 64; m <<= 1) {
        acc0 += __shfl_xor(acc0, m, 64);
        acc1 += __shfl_xor(acc1, m, 64);
        acc2 += __shfl_xor(acc2, m, 64);
        acc3 += __shfl_xor(acc3, m, 64);
        ssum += __shfl_xor(ssum, m, 64);
    }

    if (lane < 10) {   // g==0 && li<10: classes 4*li..4*li+3
        const float inv = ssum > 0.f ? 1.f / ssum : 0.f;
        const float4 b = *(const float4*)&b2[4 * li];
        float4 r;
        r.x = acc0 * inv + b.x;
        r.y = acc1 * inv + b.y;
        r.z = acc2 * inv + b.z;
        r.w = acc3 * inv + b.w;
        *(float4*)&out[(size_t)d * C + 4 * li] = r;
    }
}

extern "C" void kernel_launch(void* const* d_in, const int* in_sizes, int n_in,
                              void* d_out, int out_size, void* d_ws, size_t ws_size,
                              hipStream_t stream) {
    const float* feat = (const float*)d_in[0];
    const int*   src  = (const int*)d_in[1];
    const int*   dst  = (const int*)d_in[2];
    const float* W1   = (const float*)d_in[3];
    const float* al1  = (const float*)d_in[4];
    const float* ar1  = (const float*)d_in[5];
    const float* b1   = (const float*)d_in[6];
    const float* W2   = (const float*)d_in[7];
    const float* al2  = (const float*)d_in[8];
    const float* ar2  = (const float*)d_in[9];
    const float* b2   = (const float*)d_in[10];
    float* out = (float*)d_out;

    // ---- workspace layout ----
    u32*   h1b = (u32*)d_ws;                        // N*64 u32; reused as h2b (N*24)
    u32*   x_b = h1b + (size_t)NN * 64;             // N*64 u32 (bf16 x)
    float* el1 = (float*)(x_b + (size_t)NN * 64);   // N*4
    float* er1 = el1 + (size_t)NN * 4;              // N*4 (er2 reuses: N)
    int* row_ptr = (int*)(er1 + (size_t)NN * 4);    // N+1
    int* cursor  = row_ptr + (NN + 1);              // N
    int* deg     = cursor + NN;                     // N
    int* blk_sums = deg + NN;                       // SCAN_BLOCKS
    int* col_src = blk_sums + SCAN_BLOCKS;          // E
    u32*   h2b = h1b;
    float* er2 = er1;

    // ---- CSR build ----
    hipMemsetAsync(deg, 0, (size_t)NN * sizeof(int), stream);
    k_hist<<<(EE + 255) / 256, 256, 0, stream>>>(dst, deg);
    k_scan1<<<SCAN_BLOCKS, 256, 0, stream>>>(deg, blk_sums);
    k_scan2<<<1, 128, 0, stream>>>(blk_sums);
    k_scan3<<<SCAN_BLOCKS, 256, 0, stream>>>(deg, blk_sums, row_ptr, cursor);
    k_scatter<<<SC_NCHUNK * SC_NW, 256, 0, stream>>>(src, dst, cursor, col_src);

    // ---- layer 1 ----
    k_gemm1<<<(NN + 127) / 128, 256, 0, stream>>>(feat, W1, al1, ar1, h1b, el1, er1);
    k_agg1<<<NN / 4, 256, 0, stream>>>(row_ptr, col_src, h1b, el1, er1, b1, x_b);

    // ---- layer 2 ----
    k_gemm2<<<(NN + 127) / 128, 256, 0, stream>>>(x_b, W2, al2, ar2, h2b, er2);
    k_agg2<<<NN / 4, 256, 0, stream>>>(row_ptr, col_src, h2b, er2, b2, out);
}

// Round 2
// 510.157 us; speedup vs baseline: 1.0660x; 1.0046x over previous
//
#include <hip/hip_runtime.h>
#include <math.h>

typedef unsigned int u32;
typedef __attribute__((ext_vector_type(8))) short bf16x8;
typedef __attribute__((ext_vector_type(4))) float floatx4;

constexpr int NN = 100000;
constexpr int EE = 1600000;
constexpr int IND = 256;
constexpr int F1 = 32;
constexpr int HF = 128;   // H*F1
constexpr int C  = 40;
constexpr float SLOPE = 0.2f;

constexpr int SCAN_BLOCKS = 100;
constexpr int SCAN_CHUNK  = 1000;   // SCAN_BLOCKS * SCAN_CHUNK == NN

constexpr int SC_NW    = 8;
constexpr int SC_WINW  = (NN + SC_NW - 1) / SC_NW;
constexpr int SC_CHUNK = 8192;
constexpr int SC_NCHUNK = (EE + SC_CHUNK - 1) / SC_CHUNK;

constexpr int H2ROW = 24;  // u32 per h2b row: 20 bf16x2 pairs + el2 bits + pad

__device__ __forceinline__ u32 f2bf(float f) {
    u32 u = __float_as_uint(f);
    return (u + 0x7fffu + ((u >> 16) & 1u)) >> 16;
}
__device__ __forceinline__ float bf_lo(u32 v) { return __uint_as_float(v << 16); }
__device__ __forceinline__ float bf_hi(u32 v) { return __uint_as_float(v & 0xffff0000u); }

// hardware packed f32->bf16 (RNE), 1 inst instead of ~10
__device__ __forceinline__ u32 pkbf(float lo, float hi) {
    u32 r;
    asm("v_cvt_pk_bf16_f32 %0, %1, %2" : "=v"(r) : "v"(lo), "v"(hi));
    return r;
}

// ================= CSR build =================
__global__ __launch_bounds__(256) void k_hist(const int* __restrict__ dst,
                                              int* __restrict__ deg) {
    int e = blockIdx.x * 256 + threadIdx.x;
    if (e < EE) atomicAdd(&deg[dst[e]], 1);
}

__global__ __launch_bounds__(256) void k_scan1(const int* __restrict__ deg,
                                               int* __restrict__ blk_sums) {
    __shared__ int wsum[4];
    const int lane = threadIdx.x & 63, wid = threadIdx.x >> 6;
    const int base = blockIdx.x * SCAN_CHUNK;
    int s = 0;
    for (int i = threadIdx.x; i < SCAN_CHUNK; i += 256) s += deg[base + i];
    #pragma unroll
    for (int m = 1; m < 64; m <<= 1) s += __shfl_xor(s, m, 64);
    if (lane == 0) wsum[wid] = s;
    __syncthreads();
    if (threadIdx.x == 0)
        blk_sums[blockIdx.x] = wsum[0] + wsum[1] + wsum[2] + wsum[3];
}

__global__ __launch_bounds__(128) void k_scan2(int* __restrict__ blk_sums) {
    __shared__ int lds[128];
    const int tid = threadIdx.x;
    int v = (tid < SCAN_BLOCKS) ? blk_sums[tid] : 0;
    lds[tid] = v;
    __syncthreads();
    for (int off = 1; off < 128; off <<= 1) {
        int t = (tid >= off) ? lds[tid - off] : 0;
        __syncthreads();
        lds[tid] += t;
        __syncthreads();
    }
    if (tid < SCAN_BLOCKS) blk_sums[tid] = (tid == 0) ? 0 : lds[tid - 1];
}

__global__ __launch_bounds__(256) void k_scan3(const int* __restrict__ deg,
                                               const int* __restrict__ blk_off,
                                               int* __restrict__ row_ptr,
                                               int* __restrict__ cursor) {
    __shared__ int wsum[4];
    const int tid = threadIdx.x, lane = tid & 63, wid = tid >> 6;
    const int base = blockIdx.x * SCAN_CHUNK;
    const int g0 = tid * 4;
    int v[4];
    #pragma unroll
    for (int i = 0; i < 4; ++i) {
        int gi = g0 + i;
        v[i] = (gi < SCAN_CHUNK) ? deg[base + gi] : 0;
    }
    const int tsum = v[0] + v[1] + v[2] + v[3];
    int s = tsum;
    #pragma unroll
    for (int off = 1; off < 64; off <<= 1) {
        int t = __shfl_up(s, off, 64);
        if (lane >= off) s += t;
    }
    if (lane == 63) wsum[wid] = s;
    __syncthreads();
    int woff = 0;
    for (int w = 0; w < wid; ++w) woff += wsum[w];
    int run = blk_off[blockIdx.x] + woff + (s - tsum);
    #pragma unroll
    for (int i = 0; i < 4; ++i) {
        int gi = g0 + i;
        int idx = base + gi;
        if (gi < SCAN_CHUNK) {
            row_ptr[idx] = run;
            cursor[idx] = run;
            run += v[i];
            if (idx == NN - 1) row_ptr[NN] = run;
        }
    }
}

__global__ __launch_bounds__(256) void k_scatter(const int* __restrict__ src,
                                                 const int* __restrict__ dst,
                                                 int* __restrict__ cursor,
                                                 int* __restrict__ col_src) {
    const int w = blockIdx.x & (SC_NW - 1);
    const int chunk = blockIdx.x >> 3;
    const int lo = w * SC_WINW, hi = lo + SC_WINW;
    const int base = chunk * SC_CHUNK;
    const int lim = min(base + SC_CHUNK, EE);
    for (int i = base + threadIdx.x; i < lim; i += 256) {
        int d = dst[i];
        if (d >= lo && d < hi) {
            int p = atomicAdd(&cursor[d], 1);
            col_src[p] = src[i];
        }
    }
}

// ================= GEMM1 (MFMA bf16): h1b = bf16(feat @ W1), + el1/er1 =================
__global__ __launch_bounds__(256) void k_gemm1(const float* __restrict__ feat,
                                               const float* __restrict__ W1,
                                               const float* __restrict__ al1,
                                               const float* __restrict__ ar1,
                                               u32* __restrict__ h1b,
                                               float* __restrict__ el1,
                                               float* __restrict__ er1) {
    __shared__ u32 w1t[128 * 128];
    const int tid = threadIdx.x;
    {
        const int n = tid & 127;
        const int o0 = (tid >> 7) * 16;
        for (int i = 0; i < 16; ++i) {
            const int o = o0 + i;
            float f0 = W1[(size_t)(o * 8 + 0) * HF + n];
            float f1 = W1[(size_t)(o * 8 + 1) * HF + n];
            float f2 = W1[(size_t)(o * 8 + 2) * HF + n];
            float f3 = W1[(size_t)(o * 8 + 3) * HF + n];
            float f4 = W1[(size_t)(o * 8 + 4) * HF + n];
            float f5 = W1[(size_t)(o * 8 + 5) * HF + n];
            float f6 = W1[(size_t)(o * 8 + 6) * HF + n];
            float f7 = W1[(size_t)(o * 8 + 7) * HF + n];
            uint4 p;
            p.x = (f2bf(f1) << 16) | f2bf(f0);
            p.y = (f2bf(f3) << 16) | f2bf(f2);
            p.z = (f2bf(f5) << 16) | f2bf(f4);
            p.w = (f2bf(f7) << 16) | f2bf(f6);
            *(uint4*)&w1t[n * 128 + ((o ^ (n & 7)) << 2)] = p;
        }
    }
    __syncthreads();

    const int w = tid >> 6, lane = tid & 63;
    const int quad = lane >> 4, l15 = lane & 15;
    const int rbase = blockIdx.x * 128 + w * 32;

    // attention vectors for epilogue
    float alv[4][2], arv[4][2];
    #pragma unroll
    for (int h = 0; h < 4; ++h) {
        alv[h][0] = al1[h * F1 + l15];
        alv[h][1] = al1[h * F1 + 16 + l15];
        arv[h][0] = ar1[h * F1 + l15];
        arv[h][1] = ar1[h * F1 + 16 + l15];
    }

    floatx4 acc[2][8] = {};
    for (int ks = 0; ks < 8; ++ks) {
        bf16x8 a[2];
        #pragma unroll
        for (int ri = 0; ri < 2; ++ri) {
            int row = rbase + ri * 16 + l15;
            row = row < NN ? row : NN - 1;
            const size_t base = (size_t)row * IND + ks * 32 + quad * 8;
            const float4 f0 = *(const float4*)&feat[base];
            const float4 f1 = *(const float4*)&feat[base + 4];
            uint4 p;
            p.x = (f2bf(f0.y) << 16) | f2bf(f0.x);
            p.y = (f2bf(f0.w) << 16) | f2bf(f0.z);
            p.z = (f2bf(f1.y) << 16) | f2bf(f1.x);
            p.w = (f2bf(f1.w) << 16) | f2bf(f1.z);
            a[ri] = *(bf16x8*)&p;
        }
        const int g = ks * 4 + quad;
        #pragma unroll
        for (int ci = 0; ci < 8; ++ci) {
            const int n = ci * 16 + l15;
            uint4 bw = *(const uint4*)&w1t[n * 128 + ((g ^ (n & 7)) << 2)];
            bf16x8 b = *(bf16x8*)&bw;
            acc[0][ci] = __builtin_amdgcn_mfma_f32_16x16x32_bf16(a[0], b, acc[0][ci], 0, 0, 0);
            acc[1][ci] = __builtin_amdgcn_mfma_f32_16x16x32_bf16(a[1], b, acc[1][ci], 0, 0, 0);
        }
    }

    // ---- epilogue: pack h1b + compute el1/er1 from f32 acc ----
    #pragma unroll
    for (int ri = 0; ri < 2; ++ri) {
        #pragma unroll
        for (int r = 0; r < 4; ++r) {
            const int row = rbase + ri * 16 + quad * 4 + r;
            const bool rok = row < NN;
            #pragma unroll
            for (int h = 0; h < 4; ++h) {
                float pe = acc[ri][2 * h][r] * alv[h][0] + acc[ri][2 * h + 1][r] * alv[h][1];
                float pr = acc[ri][2 * h][r] * arv[h][0] + acc[ri][2 * h + 1][r] * arv[h][1];
                #pragma unroll
                for (int m = 1; m < 16; m <<= 1) {
                    pe += __shfl_xor(pe, m, 64);
                    pr += __shfl_xor(pr, m, 64);
                }
                if (l15 == 0 && rok) {
                    el1[row * 4 + h] = pe;
                    er1[row * 4 + h] = pr;
                }
            }
            #pragma unroll
            for (int ci = 0; ci < 8; ++ci) {
                float v = acc[ri][ci][r];
                float vn = __shfl_xor(v, 1, 64);
                if (!(lane & 1) && rok) {
                    h1b[(size_t)row * 64 + ci * 8 + (l15 >> 1)] =
                        (f2bf(vn) << 16) | f2bf(v);
                }
            }
        }
    }
}

// ================= layer-1 aggregation: 16-lane group per dst, NO cross-lane reduce ===
// Wave = 4 groups = 4 consecutive dsts. Lane li owns features 8li..8li+7 (head li>>2),
// loads one dwordx4 per edge of its group's dst. Each lane redundantly accumulates its
// head's ssum (group-uniform per head) -> no shfl reduce. Epilogue lane-parallel over
// 4 dsts. Groups diverge on degree; finished groups run masked (w=0, row-0 reads, cached).
__global__ __launch_bounds__(256) void k_agg1(const int* __restrict__ row_ptr,
                                              const int* __restrict__ col_src,
                                              const u32* __restrict__ h1b,
                                              const float* __restrict__ el1,
                                              const float* __restrict__ er1,
                                              const float* __restrict__ b1,
                                              u32* __restrict__ x_b) {
    const int lane = threadIdx.x & 63, wid = threadIdx.x >> 6;
    const int g = lane >> 4, li = lane & 15;
    const int d = blockIdx.x * 16 + wid * 4 + g;      // grid sized exactly: d < NN
    const int head = li >> 2;
    const float erd = er1[d * 4 + head];
    const int beg = row_ptr[d], end = row_ptr[d + 1];
    const u32 li16 = (u32)li << 4;     // byte offset of this lane's 16B within a row
    const u32 hoff = (u32)head << 2;   // byte offset into el1 row

    float a0 = 0.f, a1 = 0.f, a2 = 0.f, a3 = 0.f;
    float a4 = 0.f, a5 = 0.f, a6 = 0.f, a7 = 0.f;
    float ssum = 0.f;

    auto body = [&](int e) {
        const bool act = e < end;
        const int ec = act ? e : 0;
        const int s = col_src[ec];
        const u32 rb = (u32)s << 8;                      // s*256 bytes
        const uint4 v = *(const uint4*)((const char*)h1b + (rb + li16));
        float c = *(const float*)((const char*)el1 + (((u32)s << 4) + hoff)) + erd;
        c = fmaxf(c, SLOPE * c);
        float w = __expf(c);
        w = act ? w : 0.f;
        ssum += w;
        a0 += w * bf_lo(v.x); a1 += w * bf_hi(v.x);
        a2 += w * bf_lo(v.y); a3 += w * bf_hi(v.y);
        a4 += w * bf_lo(v.z); a5 += w * bf_hi(v.z);
        a6 += w * bf_lo(v.w); a7 += w * bf_hi(v.w);
    };

    int e = beg;
    while (__any(e < end)) {
        body(e);
        body(e + 1);
        e += 2;
    }

    const float inv = ssum > 0.f ? 1.f / ssum : 0.f;
    const float4 ba = *(const float4*)&b1[8 * li];
    const float4 bb = *(const float4*)&b1[8 * li + 4];
    float r0 = a0 * inv + ba.x, r1 = a1 * inv + ba.y;
    float r2 = a2 * inv + ba.z, r3 = a3 * inv + ba.w;
    float r4 = a4 * inv + bb.x, r5 = a5 * inv + bb.y;
    float r6 = a6 * inv + bb.z, r7 = a7 * inv + bb.w;
    r0 = r0 > 0.f ? r0 : __expf(r0) - 1.f;
    r1 = r1 > 0.f ? r1 : __expf(r1) - 1.f;
    r2 = r2 > 0.f ? r2 : __expf(r2) - 1.f;
    r3 = r3 > 0.f ? r3 : __expf(r3) - 1.f;
    r4 = r4 > 0.f ? r4 : __expf(r4) - 1.f;
    r5 = r5 > 0.f ? r5 : __expf(r5) - 1.f;
    r6 = r6 > 0.f ? r6 : __expf(r6) - 1.f;
    r7 = r7 > 0.f ? r7 : __expf(r7) - 1.f;
    uint4 p;
    p.x = pkbf(r0, r1);
    p.y = pkbf(r2, r3);
    p.z = pkbf(r4, r5);
    p.w = pkbf(r6, r7);
    *(uint4*)&x_b[(size_t)d * 64 + 4 * li] = p;
}

// ================= GEMM2 (MFMA bf16): h2b = pack(x @ [W2|waux_l|waux_r]) =================
// 48 padded cols: 0-39 = classes, 40 = el2 (x·(W2@al2)), 41 = er2, 42-47 zero.
__global__ __launch_bounds__(256) void k_gemm2(const u32* __restrict__ x_b,
                                               const float* __restrict__ W2,
                                               const float* __restrict__ al2,
                                               const float* __restrict__ ar2,
                                               u32* __restrict__ h2b,
                                               float* __restrict__ er2) {
    __shared__ u32 w2t[48 * 64];   // row n: 16 k-octets, octet g at ((g^(n&7))<<2)
    const int tid = threadIdx.x;
    {
        const int o = tid & 15;
        const int n0 = tid >> 4;
        for (int n = n0; n < 48; n += 16) {
            float f[8];
            #pragma unroll
            for (int j = 0; j < 8; ++j) {
                const int k = o * 8 + j;
                float v;
                if (n < C) v = W2[(size_t)k * C + n];
                else if (n == 40) {
                    v = 0.f;
                    for (int c = 0; c < C; ++c) v += W2[(size_t)k * C + c] * al2[c];
                } else if (n == 41) {
                    v = 0.f;
                    for (int c = 0; c < C; ++c) v += W2[(size_t)k * C + c] * ar2[c];
                } else v = 0.f;
                f[j] = v;
            }
            uint4 p;
            p.x = (f2bf(f[1]) << 16) | f2bf(f[0]);
            p.y = (f2bf(f[3]) << 16) | f2bf(f[2]);
            p.z = (f2bf(f[5]) << 16) | f2bf(f[4]);
            p.w = (f2bf(f[7]) << 16) | f2bf(f[6]);
            *(uint4*)&w2t[n * 64 + ((o ^ (n & 7)) << 2)] = p;
        }
    }
    __syncthreads();

    const int w = tid >> 6, lane = tid & 63;
    const int quad = lane >> 4, l15 = lane & 15;
    const int rbase = blockIdx.x * 128 + w * 32;
    floatx4 acc[2][3] = {};

    #pragma unroll
    for (int ks = 0; ks < 4; ++ks) {
        bf16x8 a[2];
        #pragma unroll
        for (int ri = 0; ri < 2; ++ri) {
            int row = rbase + ri * 16 + l15;
            row = row < NN ? row : NN - 1;
            uint4 ax = *(const uint4*)&x_b[(size_t)row * 64 + ks * 16 + quad * 4];
            a[ri] = *(bf16x8*)&ax;
        }
        const int g = ks * 4 + quad;
        #pragma unroll
        for (int ci = 0; ci < 3; ++ci) {
            const int n = ci * 16 + l15;
            uint4 bw = *(const uint4*)&w2t[n * 64 + ((g ^ (n & 7)) << 2)];
            bf16x8 b = *(bf16x8*)&bw;
            acc[0][ci] = __builtin_amdgcn_mfma_f32_16x16x32_bf16(a[0], b, acc[0][ci], 0, 0, 0);
            acc[1][ci] = __builtin_amdgcn_mfma_f32_16x16x32_bf16(a[1], b, acc[1][ci], 0, 0, 0);
        }
    }

    // epilogue: pack h2b rows; col40 -> el2 word, col41 -> er2 array
    #pragma unroll
    for (int ri = 0; ri < 2; ++ri) {
        #pragma unroll
        for (int r = 0; r < 4; ++r) {
            const int row = rbase + ri * 16 + quad * 4 + r;
            const bool rok = row < NN;
            #pragma unroll
            for (int ci = 0; ci < 3; ++ci) {
                float v = acc[ri][ci][r];
                float vn = __shfl_xor(v, 1, 64);
                if (rok) {
                    if (ci < 2) {
                        if (!(lane & 1))
                            h2b[(size_t)row * H2ROW + ci * 8 + (l15 >> 1)] =
                                (f2bf(vn) << 16) | f2bf(v);
                    } else {
                        if (!(lane & 1) && l15 < 8)
                            h2b[(size_t)row * H2ROW + 16 + (l15 >> 1)] =
                                (f2bf(vn) << 16) | f2bf(v);
                        else if (l15 == 8)
                            h2b[(size_t)row * H2ROW + 20] = __float_as_uint(v);
                        else if (l15 == 9)
                            er2[row] = v;
                    }
                }
            }
        }
    }
}

// ================= layer-2 aggregation: 16-lane group per dst, no reduce =============
// h2b row = 24 u32 (96B): u32 0..19 = 40 bf16 classes, u32 20 = el2 (f32 bits).
// Lane li<12 loads uint2 at u32 2*li (li>=12 clamp to 22 -> discarded); el2 loaded
// group-uniform. ssum identical across group's lanes -> no reduce. Lanes li<10 store.
__global__ __launch_bounds__(256) void k_agg2(const int* __restrict__ row_ptr,
                                              const int* __restrict__ col_src,
                                              const u32* __restrict__ h2b,
                                              const float* __restrict__ er2,
                                              const float* __restrict__ b2,
                                              float* __restrict__ out) {
    const int lane = threadIdx.x & 63, wid = threadIdx.x >> 6;
    const int g = lane >> 4, li = lane & 15;
    const int d = blockIdx.x * 16 + wid * 4 + g;      // grid sized exactly: d < NN
    const float erd = er2[d];
    const int beg = row_ptr[d], end = row_ptr[d + 1];
    const u32 ob = (u32)(li < 12 ? 2 * li : 22) << 2;  // byte offset within 96B row

    float a0 = 0.f, a1 = 0.f, a2 = 0.f, a3 = 0.f;
    float ssum = 0.f;

    auto body = [&](int e) {
        const bool act = e < end;
        const int ec = act ? e : 0;
        const int s = col_src[ec];
        const u32 rb = (u32)s * 96u;
        const uint2 v = *(const uint2*)((const char*)h2b + (rb + ob));
        float c = *(const float*)((const char*)h2b + rb + 80) + erd;
        c = fmaxf(c, SLOPE * c);
        float w = __expf(c);
        w = act ? w : 0.f;
        ssum += w;
        a0 += w * bf_lo(v.x); a1 += w * bf_hi(v.x);
        a2 += w * bf_lo(v.y); a3 += w * bf_hi(v.y);
    };

    int e = beg;
    while (__any(e < end)) {
        body(e);
        body(e + 1);
        e += 2;
    }

    if (li < 10) {
        const float inv = ssum > 0.f ? 1.f / ssum : 0.f;
        const float4 b = *(const float4*)&b2[4 * li];
        float4 r;
        r.x = a0 * inv + b.x;
        r.y = a1 * inv + b.y;
        r.z = a2 * inv + b.z;
        r.w = a3 * inv + b.w;
        *(float4*)&out[(size_t)d * C + 4 * li] = r;
    }
}

extern "C" void kernel_launch(void* const* d_in, const int* in_sizes, int n_in,
                              void* d_out, int out_size, void* d_ws, size_t ws_size,
                              hipStream_t stream) {
    const float* feat = (const float*)d_in[0];
    const int*   src  = (const int*)d_in[1];
    const int*   dst  = (const int*)d_in[2];
    const float* W1   = (const float*)d_in[3];
    const float* al1  = (const float*)d_in[4];
    const float* ar1  = (const float*)d_in[5];
    const float* b1   = (const float*)d_in[6];
    const float* W2   = (const float*)d_in[7];
    const float* al2  = (const float*)d_in[8];
    const float* ar2  = (const float*)d_in[9];
    const float* b2   = (const float*)d_in[10];
    float* out = (float*)d_out;

    // ---- workspace layout ----
    u32*   h1b = (u32*)d_ws;                        // N*64 u32; reused as h2b (N*24)
    u32*   x_b = h1b + (size_t)NN * 64;             // N*64 u32 (bf16 x)
    float* el1 = (float*)(x_b + (size_t)NN * 64);   // N*4
    float* er1 = el1 + (size_t)NN * 4;              // N*4 (er2 reuses: N)
    int* row_ptr = (int*)(er1 + (size_t)NN * 4);    // N+1
    int* cursor  = row_ptr + (NN + 1);              // N
    int* deg     = cursor + NN;                     // N
    int* blk_sums = deg + NN;                       // SCAN_BLOCKS
    int* col_src = blk_sums + SCAN_BLOCKS;          // E
    u32*   h2b = h1b;
    float* er2 = er1;

    // ---- CSR build ----
    hipMemsetAsync(deg, 0, (size_t)NN * sizeof(int), stream);
    k_hist<<<(EE + 255) / 256, 256, 0, stream>>>(dst, deg);
    k_scan1<<<SCAN_BLOCKS, 256, 0, stream>>>(deg, blk_sums);
    k_scan2<<<1, 128, 0, stream>>>(blk_sums);
    k_scan3<<<SCAN_BLOCKS, 256, 0, stream>>>(deg, blk_sums, row_ptr, cursor);
    k_scatter<<<SC_NCHUNK * SC_NW, 256, 0, stream>>>(src, dst, cursor, col_src);

    // ---- layer 1 ----
    k_gemm1<<<(NN + 127) / 128, 256, 0, stream>>>(feat, W1, al1, ar1, h1b, el1, er1);
    k_agg1<<<NN / 16, 256, 0, stream>>>(row_ptr, col_src, h1b, el1, er1, b1, x_b);

    // ---- layer 2 ----
    k_gemm2<<<(NN + 127) / 128, 256, 0, stream>>>(x_b, W2, al2, ar2, h2b, er2);
    k_agg2<<<NN / 16, 256, 0, stream>>>(row_ptr, col_src, h2b, er2, b2, out);
}

// Round 3
// 483.315 us; speedup vs baseline: 1.1252x; 1.0555x over previous
//
#include <hip/hip_runtime.h>
#include <math.h>

typedef unsigned int u32;
typedef __attribute__((ext_vector_type(8))) short bf16x8;
typedef __attribute__((ext_vector_type(4))) float floatx4;

constexpr int NN = 100000;
constexpr int EE = 1600000;
constexpr int IND = 256;
constexpr int F1 = 32;
constexpr int HF = 128;   // H*F1
constexpr int C  = 40;
constexpr float SLOPE = 0.2f;

constexpr int SCAN_BLOCKS = 100;
constexpr int SCAN_CHUNK  = 1000;   // SCAN_BLOCKS * SCAN_CHUNK == NN

constexpr int SC_NW    = 8;
constexpr int SC_WINW  = (NN + SC_NW - 1) / SC_NW;
constexpr int SC_CHUNK = 8192;
constexpr int SC_NCHUNK = (EE + SC_CHUNK - 1) / SC_CHUNK;

constexpr int H2ROW = 32;  // u32 per h2b row: 20 bf16x2 + el2 word + pad -> 128B line-aligned

__device__ __forceinline__ u32 f2bf(float f) {
    u32 u = __float_as_uint(f);
    return (u + 0x7fffu + ((u >> 16) & 1u)) >> 16;
}
__device__ __forceinline__ float bf_lo(u32 v) { return __uint_as_float(v << 16); }
__device__ __forceinline__ float bf_hi(u32 v) { return __uint_as_float(v & 0xffff0000u); }

// hardware packed f32->bf16 (RNE), 1 inst instead of ~11; lo -> low half
__device__ __forceinline__ u32 pkbf(float lo, float hi) {
    u32 r;
    asm("v_cvt_pk_bf16_f32 %0, %1, %2" : "=v"(r) : "v"(lo), "v"(hi));
    return r;
}

// ================= CSR build =================
__global__ __launch_bounds__(256) void k_hist(const int* __restrict__ dst,
                                              int* __restrict__ deg) {
    int e = blockIdx.x * 256 + threadIdx.x;
    if (e < EE) atomicAdd(&deg[dst[e]], 1);
}

__global__ __launch_bounds__(256) void k_scan1(const int* __restrict__ deg,
                                               int* __restrict__ blk_sums) {
    __shared__ int wsum[4];
    const int lane = threadIdx.x & 63, wid = threadIdx.x >> 6;
    const int base = blockIdx.x * SCAN_CHUNK;
    int s = 0;
    for (int i = threadIdx.x; i < SCAN_CHUNK; i += 256) s += deg[base + i];
    #pragma unroll
    for (int m = 1; m < 64; m <<= 1) s += __shfl_xor(s, m, 64);
    if (lane == 0) wsum[wid] = s;
    __syncthreads();
    if (threadIdx.x == 0)
        blk_sums[blockIdx.x] = wsum[0] + wsum[1] + wsum[2] + wsum[3];
}

__global__ __launch_bounds__(128) void k_scan2(int* __restrict__ blk_sums) {
    __shared__ int lds[128];
    const int tid = threadIdx.x;
    int v = (tid < SCAN_BLOCKS) ? blk_sums[tid] : 0;
    lds[tid] = v;
    __syncthreads();
    for (int off = 1; off < 128; off <<= 1) {
        int t = (tid >= off) ? lds[tid - off] : 0;
        __syncthreads();
        lds[tid] += t;
        __syncthreads();
    }
    if (tid < SCAN_BLOCKS) blk_sums[tid] = (tid == 0) ? 0 : lds[tid - 1];
}

__global__ __launch_bounds__(256) void k_scan3(const int* __restrict__ deg,
                                               const int* __restrict__ blk_off,
                                               int* __restrict__ row_ptr,
                                               int* __restrict__ cursor) {
    __shared__ int wsum[4];
    const int tid = threadIdx.x, lane = tid & 63, wid = tid >> 6;
    const int base = blockIdx.x * SCAN_CHUNK;
    const int g0 = tid * 4;
    int v[4];
    #pragma unroll
    for (int i = 0; i < 4; ++i) {
        int gi = g0 + i;
        v[i] = (gi < SCAN_CHUNK) ? deg[base + gi] : 0;
    }
    const int tsum = v[0] + v[1] + v[2] + v[3];
    int s = tsum;
    #pragma unroll
    for (int off = 1; off < 64; off <<= 1) {
        int t = __shfl_up(s, off, 64);
        if (lane >= off) s += t;
    }
    if (lane == 63) wsum[wid] = s;
    __syncthreads();
    int woff = 0;
    for (int w = 0; w < wid; ++w) woff += wsum[w];
    int run = blk_off[blockIdx.x] + woff + (s - tsum);
    #pragma unroll
    for (int i = 0; i < 4; ++i) {
        int gi = g0 + i;
        int idx = base + gi;
        if (gi < SCAN_CHUNK) {
            row_ptr[idx] = run;
            cursor[idx] = run;
            run += v[i];
            if (idx == NN - 1) row_ptr[NN] = run;
        }
    }
}

__global__ __launch_bounds__(256) void k_scatter(const int* __restrict__ src,
                                                 const int* __restrict__ dst,
                                                 int* __restrict__ cursor,
                                                 int* __restrict__ col_src) {
    const int w = blockIdx.x & (SC_NW - 1);
    const int chunk = blockIdx.x >> 3;
    const int lo = w * SC_WINW, hi = lo + SC_WINW;
    const int base = chunk * SC_CHUNK;
    const int lim = min(base + SC_CHUNK, EE);
    for (int i = base + threadIdx.x; i < lim; i += 256) {
        int d = dst[i];
        if (d >= lo && d < hi) {
            int p = atomicAdd(&cursor[d], 1);
            col_src[p] = src[i];
        }
    }
}

// ================= GEMM1 (MFMA bf16): h1b = bf16(feat @ W1), + el1/er1 =================
__global__ __launch_bounds__(256) void k_gemm1(const float* __restrict__ feat,
                                               const float* __restrict__ W1,
                                               const float* __restrict__ al1,
                                               const float* __restrict__ ar1,
                                               u32* __restrict__ h1b,
                                               float* __restrict__ el1,
                                               float* __restrict__ er1) {
    __shared__ u32 w1t[128 * 128];
    const int tid = threadIdx.x;
    {
        const int n = tid & 127;
        const int o0 = (tid >> 7) * 16;
        for (int i = 0; i < 16; ++i) {
            const int o = o0 + i;
            float f0 = W1[(size_t)(o * 8 + 0) * HF + n];
            float f1 = W1[(size_t)(o * 8 + 1) * HF + n];
            float f2 = W1[(size_t)(o * 8 + 2) * HF + n];
            float f3 = W1[(size_t)(o * 8 + 3) * HF + n];
            float f4 = W1[(size_t)(o * 8 + 4) * HF + n];
            float f5 = W1[(size_t)(o * 8 + 5) * HF + n];
            float f6 = W1[(size_t)(o * 8 + 6) * HF + n];
            float f7 = W1[(size_t)(o * 8 + 7) * HF + n];
            uint4 p;
            p.x = pkbf(f0, f1);
            p.y = pkbf(f2, f3);
            p.z = pkbf(f4, f5);
            p.w = pkbf(f6, f7);
            *(uint4*)&w1t[n * 128 + ((o ^ (n & 7)) << 2)] = p;
        }
    }
    __syncthreads();

    const int w = tid >> 6, lane = tid & 63;
    const int quad = lane >> 4, l15 = lane & 15;
    const int rbase = blockIdx.x * 128 + w * 32;

    // attention vectors for epilogue
    float alv[4][2], arv[4][2];
    #pragma unroll
    for (int h = 0; h < 4; ++h) {
        alv[h][0] = al1[h * F1 + l15];
        alv[h][1] = al1[h * F1 + 16 + l15];
        arv[h][0] = ar1[h * F1 + l15];
        arv[h][1] = ar1[h * F1 + 16 + l15];
    }

    floatx4 acc[2][8] = {};
    for (int ks = 0; ks < 8; ++ks) {
        bf16x8 a[2];
        #pragma unroll
        for (int ri = 0; ri < 2; ++ri) {
            int row = rbase + ri * 16 + l15;
            row = row < NN ? row : NN - 1;
            const size_t base = (size_t)row * IND + ks * 32 + quad * 8;
            const float4 f0 = *(const float4*)&feat[base];
            const float4 f1 = *(const float4*)&feat[base + 4];
            uint4 p;
            p.x = pkbf(f0.x, f0.y);
            p.y = pkbf(f0.z, f0.w);
            p.z = pkbf(f1.x, f1.y);
            p.w = pkbf(f1.z, f1.w);
            a[ri] = *(bf16x8*)&p;
        }
        const int g = ks * 4 + quad;
        #pragma unroll
        for (int ci = 0; ci < 8; ++ci) {
            const int n = ci * 16 + l15;
            uint4 bw = *(const uint4*)&w1t[n * 128 + ((g ^ (n & 7)) << 2)];
            bf16x8 b = *(bf16x8*)&bw;
            acc[0][ci] = __builtin_amdgcn_mfma_f32_16x16x32_bf16(a[0], b, acc[0][ci], 0, 0, 0);
            acc[1][ci] = __builtin_amdgcn_mfma_f32_16x16x32_bf16(a[1], b, acc[1][ci], 0, 0, 0);
        }
    }

    // ---- epilogue: pack h1b + compute el1/er1 from f32 acc ----
    #pragma unroll
    for (int ri = 0; ri < 2; ++ri) {
        #pragma unroll
        for (int r = 0; r < 4; ++r) {
            const int row = rbase + ri * 16 + quad * 4 + r;
            const bool rok = row < NN;
            #pragma unroll
            for (int h = 0; h < 4; ++h) {
                float pe = acc[ri][2 * h][r] * alv[h][0] + acc[ri][2 * h + 1][r] * alv[h][1];
                float pr = acc[ri][2 * h][r] * arv[h][0] + acc[ri][2 * h + 1][r] * arv[h][1];
                #pragma unroll
                for (int m = 1; m < 16; m <<= 1) {
                    pe += __shfl_xor(pe, m, 64);
                    pr += __shfl_xor(pr, m, 64);
                }
                if (l15 == 0 && rok) {
                    el1[row * 4 + h] = pe;
                    er1[row * 4 + h] = pr;
                }
            }
            #pragma unroll
            for (int ci = 0; ci < 8; ++ci) {
                float v = acc[ri][ci][r];
                float vn = __shfl_xor(v, 1, 64);
                if (!(lane & 1) && rok) {
                    h1b[(size_t)row * 64 + ci * 8 + (l15 >> 1)] = pkbf(v, vn);
                }
            }
        }
    }
}

// ================= layer-1 aggregation: 16-lane group per dst, 4-deep edge ILP ========
// Wave = 4 groups = 4 consecutive dsts. Lane li owns features 8li..8li+7 (head li>>2),
// loads one dwordx4 per edge of its group's dst. ssum accumulated redundantly per lane
// (group-uniform per head) -> no cross-lane reduce. 4 independent col_src->row chains
// in flight per group to cover gather latency.
__global__ __launch_bounds__(256) void k_agg1(const int* __restrict__ row_ptr,
                                              const int* __restrict__ col_src,
                                              const u32* __restrict__ h1b,
                                              const float* __restrict__ el1,
                                              const float* __restrict__ er1,
                                              const float* __restrict__ b1,
                                              u32* __restrict__ x_b) {
    const int lane = threadIdx.x & 63, wid = threadIdx.x >> 6;
    const int g = lane >> 4, li = lane & 15;
    const int d = blockIdx.x * 16 + wid * 4 + g;      // grid sized exactly: d < NN
    const int head = li >> 2;
    const float erd = er1[d * 4 + head];
    const int beg = row_ptr[d], end = row_ptr[d + 1];
    const u32 li16 = (u32)li << 4;     // byte offset of this lane's 16B within a row
    const u32 hoff = (u32)head << 2;   // byte offset into el1 row

    float a0 = 0.f, a1 = 0.f, a2 = 0.f, a3 = 0.f;
    float a4 = 0.f, a5 = 0.f, a6 = 0.f, a7 = 0.f;
    float ssum = 0.f;

    auto body = [&](int e) {
        const bool act = e < end;
        const int ec = act ? e : 0;
        const int s = col_src[ec];
        const u32 rb = (u32)s << 8;                      // s*256 bytes
        const uint4 v = *(const uint4*)((const char*)h1b + (rb + li16));
        float c = *(const float*)((const char*)el1 + (((u32)s << 4) + hoff)) + erd;
        c = fmaxf(c, SLOPE * c);
        float w = __expf(c);
        w = act ? w : 0.f;
        ssum += w;
        a0 += w * bf_lo(v.x); a1 += w * bf_hi(v.x);
        a2 += w * bf_lo(v.y); a3 += w * bf_hi(v.y);
        a4 += w * bf_lo(v.z); a5 += w * bf_hi(v.z);
        a6 += w * bf_lo(v.w); a7 += w * bf_hi(v.w);
    };

    int e = beg;
    while (__any(e < end)) {
        body(e);
        body(e + 1);
        body(e + 2);
        body(e + 3);
        e += 4;
    }

    const float inv = ssum > 0.f ? 1.f / ssum : 0.f;
    const float4 ba = *(const float4*)&b1[8 * li];
    const float4 bb = *(const float4*)&b1[8 * li + 4];
    float r0 = a0 * inv + ba.x, r1 = a1 * inv + ba.y;
    float r2 = a2 * inv + ba.z, r3 = a3 * inv + ba.w;
    float r4 = a4 * inv + bb.x, r5 = a5 * inv + bb.y;
    float r6 = a6 * inv + bb.z, r7 = a7 * inv + bb.w;
    r0 = r0 > 0.f ? r0 : __expf(r0) - 1.f;
    r1 = r1 > 0.f ? r1 : __expf(r1) - 1.f;
    r2 = r2 > 0.f ? r2 : __expf(r2) - 1.f;
    r3 = r3 > 0.f ? r3 : __expf(r3) - 1.f;
    r4 = r4 > 0.f ? r4 : __expf(r4) - 1.f;
    r5 = r5 > 0.f ? r5 : __expf(r5) - 1.f;
    r6 = r6 > 0.f ? r6 : __expf(r6) - 1.f;
    r7 = r7 > 0.f ? r7 : __expf(r7) - 1.f;
    uint4 p;
    p.x = pkbf(r0, r1);
    p.y = pkbf(r2, r3);
    p.z = pkbf(r4, r5);
    p.w = pkbf(r6, r7);
    *(uint4*)&x_b[(size_t)d * 64 + 4 * li] = p;
}

// ================= GEMM2 (MFMA bf16): h2b = pack(x @ [W2|waux_l|waux_r]) =================
// 48 padded cols: 0-39 = classes, 40 = el2 (x·(W2@al2)), 41 = er2, 42-47 zero.
// h2b rows padded to 32 u32 (128B) so each agg2 gather touches exactly one cache line.
__global__ __launch_bounds__(256) void k_gemm2(const u32* __restrict__ x_b,
                                               const float* __restrict__ W2,
                                               const float* __restrict__ al2,
                                               const float* __restrict__ ar2,
                                               u32* __restrict__ h2b,
                                               float* __restrict__ er2) {
    __shared__ u32 w2t[48 * 64];   // row n: 16 k-octets, octet g at ((g^(n&7))<<2)
    const int tid = threadIdx.x;
    {
        const int o = tid & 15;
        const int n0 = tid >> 4;
        for (int n = n0; n < 48; n += 16) {
            float f[8];
            #pragma unroll
            for (int j = 0; j < 8; ++j) {
                const int k = o * 8 + j;
                float v;
                if (n < C) v = W2[(size_t)k * C + n];
                else if (n == 40) {
                    v = 0.f;
                    for (int c = 0; c < C; ++c) v += W2[(size_t)k * C + c] * al2[c];
                } else if (n == 41) {
                    v = 0.f;
                    for (int c = 0; c < C; ++c) v += W2[(size_t)k * C + c] * ar2[c];
                } else v = 0.f;
                f[j] = v;
            }
            uint4 p;
            p.x = pkbf(f[0], f[1]);
            p.y = pkbf(f[2], f[3]);
            p.z = pkbf(f[4], f[5]);
            p.w = pkbf(f[6], f[7]);
            *(uint4*)&w2t[n * 64 + ((o ^ (n & 7)) << 2)] = p;
        }
    }
    __syncthreads();

    const int w = tid >> 6, lane = tid & 63;
    const int quad = lane >> 4, l15 = lane & 15;
    const int rbase = blockIdx.x * 128 + w * 32;
    floatx4 acc[2][3] = {};

    #pragma unroll
    for (int ks = 0; ks < 4; ++ks) {
        bf16x8 a[2];
        #pragma unroll
        for (int ri = 0; ri < 2; ++ri) {
            int row = rbase + ri * 16 + l15;
            row = row < NN ? row : NN - 1;
            uint4 ax = *(const uint4*)&x_b[(size_t)row * 64 + ks * 16 + quad * 4];
            a[ri] = *(bf16x8*)&ax;
        }
        const int g = ks * 4 + quad;
        #pragma unroll
        for (int ci = 0; ci < 3; ++ci) {
            const int n = ci * 16 + l15;
            uint4 bw = *(const uint4*)&w2t[n * 64 + ((g ^ (n & 7)) << 2)];
            bf16x8 b = *(bf16x8*)&bw;
            acc[0][ci] = __builtin_amdgcn_mfma_f32_16x16x32_bf16(a[0], b, acc[0][ci], 0, 0, 0);
            acc[1][ci] = __builtin_amdgcn_mfma_f32_16x16x32_bf16(a[1], b, acc[1][ci], 0, 0, 0);
        }
    }

    // epilogue: pack h2b rows; col40 -> el2 word, col41 -> er2 array
    #pragma unroll
    for (int ri = 0; ri < 2; ++ri) {
        #pragma unroll
        for (int r = 0; r < 4; ++r) {
            const int row = rbase + ri * 16 + quad * 4 + r;
            const bool rok = row < NN;
            #pragma unroll
            for (int ci = 0; ci < 3; ++ci) {
                float v = acc[ri][ci][r];
                float vn = __shfl_xor(v, 1, 64);
                if (rok) {
                    if (ci < 2) {
                        if (!(lane & 1))
                            h2b[(size_t)row * H2ROW + ci * 8 + (l15 >> 1)] = pkbf(v, vn);
                    } else {
                        if (!(lane & 1) && l15 < 8)
                            h2b[(size_t)row * H2ROW + 16 + (l15 >> 1)] = pkbf(v, vn);
                        else if (l15 == 8)
                            h2b[(size_t)row * H2ROW + 20] = __float_as_uint(v);
                        else if (l15 == 9)
                            er2[row] = v;
                    }
                }
            }
        }
    }
}

// ================= layer-2 aggregation: 16-lane group per dst, 4-deep edge ILP =======
// h2b row = 32 u32 (128B, line-aligned): u32 0..19 = 40 bf16 classes, u32 20 = el2.
// Lane li<12 loads uint2 at u32 2*li (li>=12 clamp to 22 -> discarded); el2 loaded
// group-uniform. ssum identical across group's lanes -> no reduce. Lanes li<10 store.
__global__ __launch_bounds__(256) void k_agg2(const int* __restrict__ row_ptr,
                                              const int* __restrict__ col_src,
                                              const u32* __restrict__ h2b,
                                              const float* __restrict__ er2,
                                              const float* __restrict__ b2,
                                              float* __restrict__ out) {
    const int lane = threadIdx.x & 63, wid = threadIdx.x >> 6;
    const int g = lane >> 4, li = lane & 15;
    const int d = blockIdx.x * 16 + wid * 4 + g;      // grid sized exactly: d < NN
    const float erd = er2[d];
    const int beg = row_ptr[d], end = row_ptr[d + 1];
    const u32 ob = (u32)(li < 12 ? 2 * li : 22) << 2;  // byte offset within 128B row

    float a0 = 0.f, a1 = 0.f, a2 = 0.f, a3 = 0.f;
    float ssum = 0.f;

    auto body = [&](int e) {
        const bool act = e < end;
        const int ec = act ? e : 0;
        const int s = col_src[ec];
        const u32 rb = (u32)s << 7;                      // s*128 bytes
        const uint2 v = *(const uint2*)((const char*)h2b + (rb + ob));
        float c = *(const float*)((const char*)h2b + rb + 80) + erd;
        c = fmaxf(c, SLOPE * c);
        float w = __expf(c);
        w = act ? w : 0.f;
        ssum += w;
        a0 += w * bf_lo(v.x); a1 += w * bf_hi(v.x);
        a2 += w * bf_lo(v.y); a3 += w * bf_hi(v.y);
    };

    int e = beg;
    while (__any(e < end)) {
        body(e);
        body(e + 1);
        body(e + 2);
        body(e + 3);
        e += 4;
    }

    if (li < 10) {
        const float inv = ssum > 0.f ? 1.f / ssum : 0.f;
        const float4 b = *(const float4*)&b2[4 * li];
        float4 r;
        r.x = a0 * inv + b.x;
        r.y = a1 * inv + b.y;
        r.z = a2 * inv + b.z;
        r.w = a3 * inv + b.w;
        *(float4*)&out[(size_t)d * C + 4 * li] = r;
    }
}

extern "C" void kernel_launch(void* const* d_in, const int* in_sizes, int n_in,
                              void* d_out, int out_size, void* d_ws, size_t ws_size,
                              hipStream_t stream) {
    const float* feat = (const float*)d_in[0];
    const int*   src  = (const int*)d_in[1];
    const int*   dst  = (const int*)d_in[2];
    const float* W1   = (const float*)d_in[3];
    const float* al1  = (const float*)d_in[4];
    const float* ar1  = (const float*)d_in[5];
    const float* b1   = (const float*)d_in[6];
    const float* W2   = (const float*)d_in[7];
    const float* al2  = (const float*)d_in[8];
    const float* ar2  = (const float*)d_in[9];
    const float* b2   = (const float*)d_in[10];
    float* out = (float*)d_out;

    // ---- workspace layout ----
    u32*   h1b = (u32*)d_ws;                        // N*64 u32; reused as h2b (N*32)
    u32*   x_b = h1b + (size_t)NN * 64;             // N*64 u32 (bf16 x)
    float* el1 = (float*)(x_b + (size_t)NN * 64);   // N*4
    float* er1 = el1 + (size_t)NN * 4;              // N*4 (er2 reuses: N)
    int* row_ptr = (int*)(er1 + (size_t)NN * 4);    // N+1
    int* cursor  = row_ptr + (NN + 1);              // N
    int* deg     = cursor + NN;                     // N
    int* blk_sums = deg + NN;                       // SCAN_BLOCKS
    int* col_src = blk_sums + SCAN_BLOCKS;          // E
    u32*   h2b = h1b;
    float* er2 = er1;

    // ---- CSR build ----
    hipMemsetAsync(deg, 0, (size_t)NN * sizeof(int), stream);
    k_hist<<<(EE + 255) / 256, 256, 0, stream>>>(dst, deg);
    k_scan1<<<SCAN_BLOCKS, 256, 0, stream>>>(deg, blk_sums);
    k_scan2<<<1, 128, 0, stream>>>(blk_sums);
    k_scan3<<<SCAN_BLOCKS, 256, 0, stream>>>(deg, blk_sums, row_ptr, cursor);
    k_scatter<<<SC_NCHUNK * SC_NW, 256, 0, stream>>>(src, dst, cursor, col_src);

    // ---- layer 1 ----
    k_gemm1<<<(NN + 127) / 128, 256, 0, stream>>>(feat, W1, al1, ar1, h1b, el1, er1);
    k_agg1<<<NN / 16, 256, 0, stream>>>(row_ptr, col_src, h1b, el1, er1, b1, x_b);

    // ---- layer 2 ----
    k_gemm2<<<(NN + 127) / 128, 256, 0, stream>>>(x_b, W2, al2, ar2, h2b, er2);
    k_agg2<<<NN / 16, 256, 0, stream>>>(row_ptr, col_src, h2b, er2, b2, out);
}

// Round 4
// 451.292 us; speedup vs baseline: 1.2050x; 1.0710x over previous
//
#include <hip/hip_runtime.h>
#include <math.h>

typedef unsigned int u32;
typedef __attribute__((ext_vector_type(8))) short bf16x8;
typedef __attribute__((ext_vector_type(4))) float floatx4;

constexpr int NN = 100000;
constexpr int EE = 1600000;
constexpr int IND = 256;
constexpr int F1 = 32;
constexpr int HF = 128;   // H*F1
constexpr int C  = 40;
constexpr float SLOPE = 0.2f;

constexpr int SCAN_BLOCKS = 100;
constexpr int SCAN_CHUNK  = 1000;   // SCAN_BLOCKS * SCAN_CHUNK == NN

constexpr int H2ROW = 32;  // u32 per h2b row: 20 bf16x2 + el2 word + pad -> 128B line-aligned

__device__ __forceinline__ u32 f2bf(float f) {
    u32 u = __float_as_uint(f);
    return (u + 0x7fffu + ((u >> 16) & 1u)) >> 16;
}
__device__ __forceinline__ float bf_lo(u32 v) { return __uint_as_float(v << 16); }
__device__ __forceinline__ float bf_hi(u32 v) { return __uint_as_float(v & 0xffff0000u); }

// hardware packed f32->bf16 (RNE), 1 inst instead of ~11; lo -> low half
__device__ __forceinline__ u32 pkbf(float lo, float hi) {
    u32 r;
    asm("v_cvt_pk_bf16_f32 %0, %1, %2" : "=v"(r) : "v"(lo), "v"(hi));
    return r;
}

// ================= CSR build =================
// hist also records each edge's arrival rank within its dst bucket (atomic return).
// rank[] lets the scatter run atomic-free in a single pass.
__global__ __launch_bounds__(256) void k_hist(const int* __restrict__ dst,
                                              int* __restrict__ deg,
                                              int* __restrict__ rank) {
    int e = blockIdx.x * 256 + threadIdx.x;
    if (e < EE) rank[e] = atomicAdd(&deg[dst[e]], 1);
}

__global__ __launch_bounds__(256) void k_scan1(const int* __restrict__ deg,
                                               int* __restrict__ blk_sums) {
    __shared__ int wsum[4];
    const int lane = threadIdx.x & 63, wid = threadIdx.x >> 6;
    const int base = blockIdx.x * SCAN_CHUNK;
    int s = 0;
    for (int i = threadIdx.x; i < SCAN_CHUNK; i += 256) s += deg[base + i];
    #pragma unroll
    for (int m = 1; m < 64; m <<= 1) s += __shfl_xor(s, m, 64);
    if (lane == 0) wsum[wid] = s;
    __syncthreads();
    if (threadIdx.x == 0)
        blk_sums[blockIdx.x] = wsum[0] + wsum[1] + wsum[2] + wsum[3];
}

__global__ __launch_bounds__(128) void k_scan2(int* __restrict__ blk_sums) {
    __shared__ int lds[128];
    const int tid = threadIdx.x;
    int v = (tid < SCAN_BLOCKS) ? blk_sums[tid] : 0;
    lds[tid] = v;
    __syncthreads();
    for (int off = 1; off < 128; off <<= 1) {
        int t = (tid >= off) ? lds[tid - off] : 0;
        __syncthreads();
        lds[tid] += t;
        __syncthreads();
    }
    if (tid < SCAN_BLOCKS) blk_sums[tid] = (tid == 0) ? 0 : lds[tid - 1];
}

__global__ __launch_bounds__(256) void k_scan3(const int* __restrict__ deg,
                                               const int* __restrict__ blk_off,
                                               int* __restrict__ row_ptr) {
    __shared__ int wsum[4];
    const int tid = threadIdx.x, lane = tid & 63, wid = tid >> 6;
    const int base = blockIdx.x * SCAN_CHUNK;
    const int g0 = tid * 4;
    int v[4];
    #pragma unroll
    for (int i = 0; i < 4; ++i) {
        int gi = g0 + i;
        v[i] = (gi < SCAN_CHUNK) ? deg[base + gi] : 0;
    }
    const int tsum = v[0] + v[1] + v[2] + v[3];
    int s = tsum;
    #pragma unroll
    for (int off = 1; off < 64; off <<= 1) {
        int t = __shfl_up(s, off, 64);
        if (lane >= off) s += t;
    }
    if (lane == 63) wsum[wid] = s;
    __syncthreads();
    int woff = 0;
    for (int w = 0; w < wid; ++w) woff += wsum[w];
    int run = blk_off[blockIdx.x] + woff + (s - tsum);
    #pragma unroll
    for (int i = 0; i < 4; ++i) {
        int gi = g0 + i;
        int idx = base + gi;
        if (gi < SCAN_CHUNK) {
            row_ptr[idx] = run;
            run += v[i];
            if (idx == NN - 1) row_ptr[NN] = run;
        }
    }
}

// single-pass atomic-free scatter: p = row_ptr[dst] + rank; 4 edges/thread, int4 loads
__global__ __launch_bounds__(256) void k_scatter(const int* __restrict__ src,
                                                 const int* __restrict__ dst,
                                                 const int* __restrict__ rank,
                                                 const int* __restrict__ row_ptr,
                                                 int* __restrict__ col_src) {
    const int i = blockIdx.x * 256 + threadIdx.x;   // edge-quad index
    const int e = i * 4;
    if (e < EE) {   // EE % 4 == 0: quads never straddle the end
        const int4 d4 = *(const int4*)&dst[e];
        const int4 s4 = *(const int4*)&src[e];
        const int4 r4 = *(const int4*)&rank[e];
        col_src[row_ptr[d4.x] + r4.x] = s4.x;
        col_src[row_ptr[d4.y] + r4.y] = s4.y;
        col_src[row_ptr[d4.z] + r4.z] = s4.z;
        col_src[row_ptr[d4.w] + r4.w] = s4.w;
    }
}

// ================= GEMM1 (MFMA bf16): h1b = bf16(feat @ W1), + el1/er1 =================
__global__ __launch_bounds__(256) void k_gemm1(const float* __restrict__ feat,
                                               const float* __restrict__ W1,
                                               const float* __restrict__ al1,
                                               const float* __restrict__ ar1,
                                               u32* __restrict__ h1b,
                                               float* __restrict__ el1,
                                               float* __restrict__ er1) {
    __shared__ u32 w1t[128 * 128];
    const int tid = threadIdx.x;
    {
        const int n = tid & 127;
        const int o0 = (tid >> 7) * 16;
        for (int i = 0; i < 16; ++i) {
            const int o = o0 + i;
            float f0 = W1[(size_t)(o * 8 + 0) * HF + n];
            float f1 = W1[(size_t)(o * 8 + 1) * HF + n];
            float f2 = W1[(size_t)(o * 8 + 2) * HF + n];
            float f3 = W1[(size_t)(o * 8 + 3) * HF + n];
            float f4 = W1[(size_t)(o * 8 + 4) * HF + n];
            float f5 = W1[(size_t)(o * 8 + 5) * HF + n];
            float f6 = W1[(size_t)(o * 8 + 6) * HF + n];
            float f7 = W1[(size_t)(o * 8 + 7) * HF + n];
            uint4 p;
            p.x = pkbf(f0, f1);
            p.y = pkbf(f2, f3);
            p.z = pkbf(f4, f5);
            p.w = pkbf(f6, f7);
            *(uint4*)&w1t[n * 128 + ((o ^ (n & 7)) << 2)] = p;
        }
    }
    __syncthreads();

    const int w = tid >> 6, lane = tid & 63;
    const int quad = lane >> 4, l15 = lane & 15;
    const int rbase = blockIdx.x * 128 + w * 32;

    // attention vectors for epilogue
    float alv[4][2], arv[4][2];
    #pragma unroll
    for (int h = 0; h < 4; ++h) {
        alv[h][0] = al1[h * F1 + l15];
        alv[h][1] = al1[h * F1 + 16 + l15];
        arv[h][0] = ar1[h * F1 + l15];
        arv[h][1] = ar1[h * F1 + 16 + l15];
    }

    floatx4 acc[2][8] = {};
    for (int ks = 0; ks < 8; ++ks) {
        bf16x8 a[2];
        #pragma unroll
        for (int ri = 0; ri < 2; ++ri) {
            int row = rbase + ri * 16 + l15;
            row = row < NN ? row : NN - 1;
            const size_t base = (size_t)row * IND + ks * 32 + quad * 8;
            const float4 f0 = *(const float4*)&feat[base];
            const float4 f1 = *(const float4*)&feat[base + 4];
            uint4 p;
            p.x = pkbf(f0.x, f0.y);
            p.y = pkbf(f0.z, f0.w);
            p.z = pkbf(f1.x, f1.y);
            p.w = pkbf(f1.z, f1.w);
            a[ri] = *(bf16x8*)&p;
        }
        const int g = ks * 4 + quad;
        #pragma unroll
        for (int ci = 0; ci < 8; ++ci) {
            const int n = ci * 16 + l15;
            uint4 bw = *(const uint4*)&w1t[n * 128 + ((g ^ (n & 7)) << 2)];
            bf16x8 b = *(bf16x8*)&bw;
            acc[0][ci] = __builtin_amdgcn_mfma_f32_16x16x32_bf16(a[0], b, acc[0][ci], 0, 0, 0);
            acc[1][ci] = __builtin_amdgcn_mfma_f32_16x16x32_bf16(a[1], b, acc[1][ci], 0, 0, 0);
        }
    }

    // ---- epilogue: pack h1b + compute el1/er1 from f32 acc ----
    #pragma unroll
    for (int ri = 0; ri < 2; ++ri) {
        #pragma unroll
        for (int r = 0; r < 4; ++r) {
            const int row = rbase + ri * 16 + quad * 4 + r;
            const bool rok = row < NN;
            #pragma unroll
            for (int h = 0; h < 4; ++h) {
                float pe = acc[ri][2 * h][r] * alv[h][0] + acc[ri][2 * h + 1][r] * alv[h][1];
                float pr = acc[ri][2 * h][r] * arv[h][0] + acc[ri][2 * h + 1][r] * arv[h][1];
                #pragma unroll
                for (int m = 1; m < 16; m <<= 1) {
                    pe += __shfl_xor(pe, m, 64);
                    pr += __shfl_xor(pr, m, 64);
                }
                if (l15 == 0 && rok) {
                    el1[row * 4 + h] = pe;
                    er1[row * 4 + h] = pr;
                }
            }
            #pragma unroll
            for (int ci = 0; ci < 8; ++ci) {
                float v = acc[ri][ci][r];
                float vn = __shfl_xor(v, 1, 64);
                if (!(lane & 1) && rok) {
                    h1b[(size_t)row * 64 + ci * 8 + (l15 >> 1)] = pkbf(v, vn);
                }
            }
        }
    }
}

// ================= layer-1 aggregation: 16-lane group per dst, 4-deep edge ILP ========
__global__ __launch_bounds__(256) void k_agg1(const int* __restrict__ row_ptr,
                                              const int* __restrict__ col_src,
                                              const u32* __restrict__ h1b,
                                              const float* __restrict__ el1,
                                              const float* __restrict__ er1,
                                              const float* __restrict__ b1,
                                              u32* __restrict__ x_b) {
    const int lane = threadIdx.x & 63, wid = threadIdx.x >> 6;
    const int g = lane >> 4, li = lane & 15;
    const int d = blockIdx.x * 16 + wid * 4 + g;      // grid sized exactly: d < NN
    const int head = li >> 2;
    const float erd = er1[d * 4 + head];
    const int beg = row_ptr[d], end = row_ptr[d + 1];
    const u32 li16 = (u32)li << 4;     // byte offset of this lane's 16B within a row
    const u32 hoff = (u32)head << 2;   // byte offset into el1 row

    float a0 = 0.f, a1 = 0.f, a2 = 0.f, a3 = 0.f;
    float a4 = 0.f, a5 = 0.f, a6 = 0.f, a7 = 0.f;
    float ssum = 0.f;

    auto body = [&](int e) {
        const bool act = e < end;
        const int ec = act ? e : 0;
        const int s = col_src[ec];
        const u32 rb = (u32)s << 8;                      // s*256 bytes
        const uint4 v = *(const uint4*)((const char*)h1b + (rb + li16));
        float c = *(const float*)((const char*)el1 + (((u32)s << 4) + hoff)) + erd;
        c = fmaxf(c, SLOPE * c);
        float w = __expf(c);
        w = act ? w : 0.f;
        ssum += w;
        a0 += w * bf_lo(v.x); a1 += w * bf_hi(v.x);
        a2 += w * bf_lo(v.y); a3 += w * bf_hi(v.y);
        a4 += w * bf_lo(v.z); a5 += w * bf_hi(v.z);
        a6 += w * bf_lo(v.w); a7 += w * bf_hi(v.w);
    };

    int e = beg;
    while (__any(e < end)) {
        body(e);
        body(e + 1);
        body(e + 2);
        body(e + 3);
        e += 4;
    }

    const float inv = ssum > 0.f ? 1.f / ssum : 0.f;
    const float4 ba = *(const float4*)&b1[8 * li];
    const float4 bb = *(const float4*)&b1[8 * li + 4];
    float r0 = a0 * inv + ba.x, r1 = a1 * inv + ba.y;
    float r2 = a2 * inv + ba.z, r3 = a3 * inv + ba.w;
    float r4 = a4 * inv + bb.x, r5 = a5 * inv + bb.y;
    float r6 = a6 * inv + bb.z, r7 = a7 * inv + bb.w;
    r0 = r0 > 0.f ? r0 : __expf(r0) - 1.f;
    r1 = r1 > 0.f ? r1 : __expf(r1) - 1.f;
    r2 = r2 > 0.f ? r2 : __expf(r2) - 1.f;
    r3 = r3 > 0.f ? r3 : __expf(r3) - 1.f;
    r4 = r4 > 0.f ? r4 : __expf(r4) - 1.f;
    r5 = r5 > 0.f ? r5 : __expf(r5) - 1.f;
    r6 = r6 > 0.f ? r6 : __expf(r6) - 1.f;
    r7 = r7 > 0.f ? r7 : __expf(r7) - 1.f;
    uint4 p;
    p.x = pkbf(r0, r1);
    p.y = pkbf(r2, r3);
    p.z = pkbf(r4, r5);
    p.w = pkbf(r6, r7);
    *(uint4*)&x_b[(size_t)d * 64 + 4 * li] = p;
}

// ================= GEMM2 (MFMA bf16): h2b = pack(x @ [W2|waux_l|waux_r]) =================
// 48 padded cols: 0-39 = classes, 40 = el2 (x·(W2@al2)), 41 = er2, 42-47 zero.
// h2b rows padded to 32 u32 (128B) so each agg2 gather touches exactly one cache line.
__global__ __launch_bounds__(256) void k_gemm2(const u32* __restrict__ x_b,
                                               const float* __restrict__ W2,
                                               const float* __restrict__ al2,
                                               const float* __restrict__ ar2,
                                               u32* __restrict__ h2b,
                                               float* __restrict__ er2) {
    __shared__ u32 w2t[48 * 64];   // row n: 16 k-octets, octet g at ((g^(n&7))<<2)
    const int tid = threadIdx.x;
    {
        const int o = tid & 15;
        const int n0 = tid >> 4;
        for (int n = n0; n < 48; n += 16) {
            float f[8];
            #pragma unroll
            for (int j = 0; j < 8; ++j) {
                const int k = o * 8 + j;
                float v;
                if (n < C) v = W2[(size_t)k * C + n];
                else if (n == 40) {
                    v = 0.f;
                    for (int c = 0; c < C; ++c) v += W2[(size_t)k * C + c] * al2[c];
                } else if (n == 41) {
                    v = 0.f;
                    for (int c = 0; c < C; ++c) v += W2[(size_t)k * C + c] * ar2[c];
                } else v = 0.f;
                f[j] = v;
            }
            uint4 p;
            p.x = pkbf(f[0], f[1]);
            p.y = pkbf(f[2], f[3]);
            p.z = pkbf(f[4], f[5]);
            p.w = pkbf(f[6], f[7]);
            *(uint4*)&w2t[n * 64 + ((o ^ (n & 7)) << 2)] = p;
        }
    }
    __syncthreads();

    const int w = tid >> 6, lane = tid & 63;
    const int quad = lane >> 4, l15 = lane & 15;
    const int rbase = blockIdx.x * 128 + w * 32;
    floatx4 acc[2][3] = {};

    #pragma unroll
    for (int ks = 0; ks < 4; ++ks) {
        bf16x8 a[2];
        #pragma unroll
        for (int ri = 0; ri < 2; ++ri) {
            int row = rbase + ri * 16 + l15;
            row = row < NN ? row : NN - 1;
            uint4 ax = *(const uint4*)&x_b[(size_t)row * 64 + ks * 16 + quad * 4];
            a[ri] = *(bf16x8*)&ax;
        }
        const int g = ks * 4 + quad;
        #pragma unroll
        for (int ci = 0; ci < 3; ++ci) {
            const int n = ci * 16 + l15;
            uint4 bw = *(const uint4*)&w2t[n * 64 + ((g ^ (n & 7)) << 2)];
            bf16x8 b = *(bf16x8*)&bw;
            acc[0][ci] = __builtin_amdgcn_mfma_f32_16x16x32_bf16(a[0], b, acc[0][ci], 0, 0, 0);
            acc[1][ci] = __builtin_amdgcn_mfma_f32_16x16x32_bf16(a[1], b, acc[1][ci], 0, 0, 0);
        }
    }

    // epilogue: pack h2b rows; col40 -> el2 word, col41 -> er2 array
    #pragma unroll
    for (int ri = 0; ri < 2; ++ri) {
        #pragma unroll
        for (int r = 0; r < 4; ++r) {
            const int row = rbase + ri * 16 + quad * 4 + r;
            const bool rok = row < NN;
            #pragma unroll
            for (int ci = 0; ci < 3; ++ci) {
                float v = acc[ri][ci][r];
                float vn = __shfl_xor(v, 1, 64);
                if (rok) {
                    if (ci < 2) {
                        if (!(lane & 1))
                            h2b[(size_t)row * H2ROW + ci * 8 + (l15 >> 1)] = pkbf(v, vn);
                    } else {
                        if (!(lane & 1) && l15 < 8)
                            h2b[(size_t)row * H2ROW + 16 + (l15 >> 1)] = pkbf(v, vn);
                        else if (l15 == 8)
                            h2b[(size_t)row * H2ROW + 20] = __float_as_uint(v);
                        else if (l15 == 9)
                            er2[row] = v;
                    }
                }
            }
        }
    }
}

// ================= layer-2 aggregation: 16-lane group per dst, 4-deep edge ILP =======
__global__ __launch_bounds__(256) void k_agg2(const int* __restrict__ row_ptr,
                                              const int* __restrict__ col_src,
                                              const u32* __restrict__ h2b,
                                              const float* __restrict__ er2,
                                              const float* __restrict__ b2,
                                              float* __restrict__ out) {
    const int lane = threadIdx.x & 63, wid = threadIdx.x >> 6;
    const int g = lane >> 4, li = lane & 15;
    const int d = blockIdx.x * 16 + wid * 4 + g;      // grid sized exactly: d < NN
    const float erd = er2[d];
    const int beg = row_ptr[d], end = row_ptr[d + 1];
    const u32 ob = (u32)(li < 12 ? 2 * li : 22) << 2;  // byte offset within 128B row

    float a0 = 0.f, a1 = 0.f, a2 = 0.f, a3 = 0.f;
    float ssum = 0.f;

    auto body = [&](int e) {
        const bool act = e < end;
        const int ec = act ? e : 0;
        const int s = col_src[ec];
        const u32 rb = (u32)s << 7;                      // s*128 bytes
        const uint2 v = *(const uint2*)((const char*)h2b + (rb + ob));
        float c = *(const float*)((const char*)h2b + rb + 80) + erd;
        c = fmaxf(c, SLOPE * c);
        float w = __expf(c);
        w = act ? w : 0.f;
        ssum += w;
        a0 += w * bf_lo(v.x); a1 += w * bf_hi(v.x);
        a2 += w * bf_lo(v.y); a3 += w * bf_hi(v.y);
    };

    int e = beg;
    while (__any(e < end)) {
        body(e);
        body(e + 1);
        body(e + 2);
        body(e + 3);
        e += 4;
    }

    if (li < 10) {
        const float inv = ssum > 0.f ? 1.f / ssum : 0.f;
        const float4 b = *(const float4*)&b2[4 * li];
        float4 r;
        r.x = a0 * inv + b.x;
        r.y = a1 * inv + b.y;
        r.z = a2 * inv + b.z;
        r.w = a3 * inv + b.w;
        *(float4*)&out[(size_t)d * C + 4 * li] = r;
    }
}

extern "C" void kernel_launch(void* const* d_in, const int* in_sizes, int n_in,
                              void* d_out, int out_size, void* d_ws, size_t ws_size,
                              hipStream_t stream) {
    const float* feat = (const float*)d_in[0];
    const int*   src  = (const int*)d_in[1];
    const int*   dst  = (const int*)d_in[2];
    const float* W1   = (const float*)d_in[3];
    const float* al1  = (const float*)d_in[4];
    const float* ar1  = (const float*)d_in[5];
    const float* b1   = (const float*)d_in[6];
    const float* W2   = (const float*)d_in[7];
    const float* al2  = (const float*)d_in[8];
    const float* ar2  = (const float*)d_in[9];
    const float* b2   = (const float*)d_in[10];
    float* out = (float*)d_out;

    // ---- workspace layout ----
    u32*   h1b = (u32*)d_ws;                        // N*64 u32; reused as h2b (N*32)
    u32*   x_b = h1b + (size_t)NN * 64;             // N*64 u32 (bf16 x)
    float* el1 = (float*)(x_b + (size_t)NN * 64);   // N*4
    float* er1 = el1 + (size_t)NN * 4;              // N*4 (er2 reuses: N)
    int* row_ptr = (int*)(er1 + (size_t)NN * 4);    // N+1
    int* deg     = row_ptr + (NN + 1);              // N
    int* blk_sums = deg + NN;                       // SCAN_BLOCKS
    int* col_src = blk_sums + SCAN_BLOCKS;          // E
    int* rank = (int*)h1b;                          // E ints, aliases h1b (dead until gemm1)
    u32*   h2b = h1b;
    float* er2 = er1;

    // ---- CSR build (atomic-free single-pass scatter via hist-assigned ranks) ----
    hipMemsetAsync(deg, 0, (size_t)NN * sizeof(int), stream);
    k_hist<<<(EE + 255) / 256, 256, 0, stream>>>(dst, deg, rank);
    k_scan1<<<SCAN_BLOCKS, 256, 0, stream>>>(deg, blk_sums);
    k_scan2<<<1, 128, 0, stream>>>(blk_sums);
    k_scan3<<<SCAN_BLOCKS, 256, 0, stream>>>(deg, blk_sums, row_ptr);
    k_scatter<<<(EE / 4 + 255) / 256, 256, 0, stream>>>(src, dst, rank, row_ptr, col_src);

    // ---- layer 1 ----
    k_gemm1<<<(NN + 127) / 128, 256, 0, stream>>>(feat, W1, al1, ar1, h1b, el1, er1);
    k_agg1<<<NN / 16, 256, 0, stream>>>(row_ptr, col_src, h1b, el1, er1, b1, x_b);

    // ---- layer 2 ----
    k_gemm2<<<(NN + 127) / 128, 256, 0, stream>>>(x_b, W2, al2, ar2, h2b, er2);
    k_agg2<<<NN / 16, 256, 0, stream>>>(row_ptr, col_src, h2b, er2, b2, out);
}